// Round 1
// baseline (331.768 us; speedup 1.0000x reference)
//
#include <hip/hip_runtime.h>
#include <stdint.h>
#include <stddef.h>

typedef int v4i  __attribute__((ext_vector_type(4)));
typedef int v16i __attribute__((ext_vector_type(16)));
typedef _Float16 vh8 __attribute__((ext_vector_type(8)));

#define GELU_A   (-0.2888f)
#define GELU_B   (-1.769f)
#define INV_SQRT2 0.70710678118654752440f

// async 16B global->LDS (lane i's 16B lands at ldsbase + i*16; ldsbase wave-uniform)
#define GLD16(gp, lp) __builtin_amdgcn_global_load_lds( \
    (const __attribute__((address_space(1))) unsigned int*)(gp), \
    (__attribute__((address_space(3))) unsigned int*)(lp), 16, 0, 0)

// gfx9 s_waitcnt immediates: vmcnt[3:0]=bits3:0, expcnt=bits6:4, lgkmcnt=bits11:8
#define WAIT_VM6 0x0F76   // vmcnt(6)
#define WAIT_VM0 0x0F70   // vmcnt(0)

// scalar slots: sc[0]=enc(xmin) sc[1]=enc(gmin)  [init 0xFFFFFFFF]
//               sc[2]=enc(xmax) sc[3]=|w1|max bits sc[4]=|w2|max bits sc[5]=enc(gmax) [init 0]

__device__ __forceinline__ unsigned enc_f(float f){
  unsigned u = __float_as_uint(f);
  return (u & 0x80000000u) ? ~u : (u | 0x80000000u);
}
__device__ __forceinline__ float dec_f(unsigned e){
  unsigned u = (e & 0x80000000u) ? (e & 0x7FFFFFFFu) : ~e;
  return __uint_as_float(u);
}

__device__ __forceinline__ float int_gelu_f(float x){
  float t = x * INV_SQRT2;
  float at = fminf(fabsf(t), 1.769f);
  float u = at + GELU_B;                 // in [-1.769, 0]
  float p = GELU_A * (u * u) + 1.0f;
  float L = (t > 0.0f) ? p : ((t < 0.0f) ? -p : 0.0f);
  return x * 0.5f * (1.0f + L);
}

// blocks [0,1024): x min/max; [1024,1152): absmax w1 -> sc[3]; [1152,1280): absmax w2 -> sc[4]
__global__ __launch_bounds__(256) void reduce_stats(
    const float4* __restrict__ x, int nx4,
    const float4* __restrict__ w1, int n14,
    const float4* __restrict__ w2, int n24,
    unsigned* __restrict__ sc)
{
  __shared__ float ra[256], rb[256];
  const int tid = threadIdx.x;
  const int b = blockIdx.x;
  if (b < 1024){
    float lmin = 3.4e38f, lmax = -3.4e38f;
    for (long i = (long)b * 256 + tid; i < nx4; i += 1024L * 256L){
      float4 v = x[i];
      lmin = fminf(lmin, fminf(fminf(v.x, v.y), fminf(v.z, v.w)));
      lmax = fmaxf(lmax, fmaxf(fmaxf(v.x, v.y), fmaxf(v.z, v.w)));
    }
    ra[tid] = lmin; rb[tid] = lmax;
    __syncthreads();
    for (int s = 128; s > 0; s >>= 1){
      if (tid < s){ ra[tid] = fminf(ra[tid], ra[tid + s]); rb[tid] = fmaxf(rb[tid], rb[tid + s]); }
      __syncthreads();
    }
    if (tid == 0){
      atomicMin(&sc[0], enc_f(ra[0]));
      atomicMax(&sc[2], enc_f(rb[0]));
    }
  } else {
    const float4* w; int n4; int slot; int bl;
    if (b < 1152){ w = w1; n4 = n14; slot = 3; bl = b - 1024; }
    else         { w = w2; n4 = n24; slot = 4; bl = b - 1152; }
    float la = 0.0f;
    for (long i = (long)bl * 256 + tid; i < n4; i += 128L * 256L){
      float4 v = w[i];
      la = fmaxf(la, fmaxf(fmaxf(fabsf(v.x), fabsf(v.y)), fmaxf(fabsf(v.z), fabsf(v.w))));
    }
    ra[tid] = la;
    __syncthreads();
    for (int s = 128; s > 0; s >>= 1){
      if (tid < s) ra[tid] = fmaxf(ra[tid], ra[tid + s]);
      __syncthreads();
    }
    if (tid == 0) atomicMax(&sc[slot], __float_as_uint(ra[0]));
  }
}

// fused: blocks [0,2048) act-quant x -> qx ((q-128) int8, packed u32);
//        blocks [2048, 2048+H+D) weight-quant rows (+row sums)
__global__ __launch_bounds__(256) void quant_all(
    const float4* __restrict__ x, unsigned* __restrict__ qx, long nx4,
    const float* __restrict__ w1, const float* __restrict__ w2,
    int8_t* __restrict__ qw1, int8_t* __restrict__ qw2,
    int* __restrict__ rs1, int* __restrict__ rs2,
    const unsigned* __restrict__ sc, int H, int D)
{
  const int tid = threadIdx.x;
  const int b = blockIdx.x;
  if (b < 2048){
    const float vmin = dec_f(sc[0]);
    const float vmax = dec_f(sc[2]);
    const float s  = fmaxf(vmax - vmin, 1e-8f) / 255.0f;
    const float zp = rintf(-vmin / s);
    for (long i = (long)b * 256 + tid; i < nx4; i += 2048L * 256L){
      float4 v = x[i];
      int q0 = (int)fminf(fmaxf(rintf(v.x / s) + zp, 0.0f), 255.0f) - 128;
      int q1 = (int)fminf(fmaxf(rintf(v.y / s) + zp, 0.0f), 255.0f) - 128;
      int q2 = (int)fminf(fmaxf(rintf(v.z / s) + zp, 0.0f), 255.0f) - 128;
      int q3 = (int)fminf(fmaxf(rintf(v.w / s) + zp, 0.0f), 255.0f) - 128;
      qx[i] = ((unsigned)(q0 & 255)) | ((unsigned)(q1 & 255) << 8) |
              ((unsigned)(q2 & 255) << 16) | ((unsigned)(q3 & 255) << 24);
    }
  } else {
    __shared__ int red[256];
    const int wb = b - 2048;
    const float* w; int8_t* q; int* rs; int K; int n; float s;
    if (wb < H){ w = w1; q = qw1; rs = rs1; K = D; n = wb;
                 s = fmaxf(__uint_as_float(sc[3]), 1e-8f) / 127.0f; }
    else       { w = w2; q = qw2; rs = rs2; K = H; n = wb - H;
                 s = fmaxf(__uint_as_float(sc[4]), 1e-8f) / 127.0f; }
    int sum = 0;
    for (int k = tid; k < K; k += 256){
      float v = w[(size_t)n * K + k];
      float qf = fminf(fmaxf(rintf(v / s), -128.0f), 127.0f);
      int qi = (int)qf;
      q[(size_t)n * K + k] = (int8_t)qi;
      sum += qi;
    }
    red[tid] = sum;
    __syncthreads();
    for (int st = 128; st > 0; st >>= 1){
      if (tid < st) red[tid] += red[tid + st];
      __syncthreads();
    }
    if (tid == 0) rs[n] = red[0];
  }
}

// elementwise: fp16 g -> int8 qg ((q-128)), using g stats
__global__ __launch_bounds__(256) void quant_g(
    const vh8* __restrict__ g, uint2* __restrict__ qg, long n8,
    const unsigned* __restrict__ sc)
{
  const float gmin = dec_f(sc[1]), gmax = dec_f(sc[5]);
  const float qs  = fmaxf(gmax - gmin, 1e-8f) / 255.0f;
  const float qzp = rintf(-gmin / qs);
  const long stride = (long)gridDim.x * blockDim.x;
  for (long i = (long)blockIdx.x * blockDim.x + threadIdx.x; i < n8; i += stride){
    vh8 v = g[i];
    unsigned lo = 0, hi = 0;
#pragma unroll
    for (int j = 0; j < 4; j++){
      int q = (int)fminf(fmaxf(rintf((float)v[j] / qs) + qzp, 0.0f), 255.0f) - 128;
      lo |= ((unsigned)(q & 255)) << (8 * j);
    }
#pragma unroll
    for (int j = 0; j < 4; j++){
      int q = (int)fminf(fmaxf(rintf((float)v[4 + j] / qs) + qzp, 0.0f), 255.0f) - 128;
      hi |= ((unsigned)(q & 255)) << (8 * j);
    }
    uint2 o; o.x = lo; o.y = hi;
    qg[i] = o;
  }
}

// MODE 0: h->gelu-> g min/max atomics only (no store)          [fallback pass A]
// MODE 3: h->gelu-> store g fp16 + g min/max atomics            [main pass A]
// MODE 2: h->gelu-> quantize with g stats -> store int8 (q-128) [fallback pass B]
// MODE 1: h + bias -> store fp32 out                            [GEMM2]
//
// 128M x 256N tile, BK=64, mfma_i32_32x32x32_i8, 4 waves each 64x128 (2x4 of 32x32).
// Per wave per K-step: 12 ds_read_b128 feed 16 MFMAs (768 B LDS per MFMA vs 1024
// in the old 64x64 wave tile) -> doubled MFMA work per barrier at ~same sync cost.
// 3-stage software pipeline, 3 LDS buffers (72KB -> 2 blocks/CU); per iter:
// s_waitcnt vmcnt(6) (own tile-kt's 6 DMAs done, kt+1's in flight) -> raw s_barrier
// -> ds_read frags -> issue DMA kt+2 -> MFMAs. Never vmcnt(0) in steady state.
template<int MODE>
__global__ __launch_bounds__(256, 2) void gemm_i8(
    const int8_t* __restrict__ A, const int8_t* __restrict__ Bm,
    const int* __restrict__ rowsum, const float* __restrict__ bias,
    void* __restrict__ Cout, int M, int N, int K,
    unsigned* __restrict__ sc)
{
  __shared__ __align__(16) int8_t lds[3][24576];   // per buf: A(128x64) @0, B(256x64) @8192

  const int tid  = threadIdx.x;
  const int lane = tid & 63;
  const int wave = tid >> 6;
  const int l31  = lane & 31;
  const int kh   = lane >> 5;          // 0/1 : which 16B half of a 32-k block
  const int n0   = blockIdx.x * 256;
  const int m0   = blockIdx.y * 128;
  const int wm   = (wave >> 1) * 64;   // wave M offset (0/64)
  const int wn   = (wave & 1) * 128;   // wave N offset (0/128)

  // staging: wave w stages A rows [32w,32w+32) (2 instrs of 16 rows) and
  // B rows [64w,64w+64) (4 instrs of 16 rows).
  // lane L -> row rbase+(L>>2), LDS slot L&3, src chunk (L&3)^((row>>1)&3).
  int aoffs[2], boffs[4];
  const int ldstA[2] = { wave * 2048, wave * 2048 + 1024 };
  const int ldstB[4] = { 8192 + wave * 4096,        8192 + wave * 4096 + 1024,
                         8192 + wave * 4096 + 2048, 8192 + wave * 4096 + 3072 };
#pragma unroll
  for (int t = 0; t < 2; t++){
    int rowl = wave * 32 + t * 16 + (lane >> 2);       // local tile row 0..127
    int csw  = ((lane & 3) ^ ((rowl >> 1) & 3)) << 4;  // swizzled source chunk
    int ga = m0 + rowl; if (ga >= M) ga = M - 1;
    aoffs[t] = ga * K + csw;
  }
#pragma unroll
  for (int t = 0; t < 4; t++){
    int rowl = wave * 64 + t * 16 + (lane >> 2);       // local tile row 0..255
    int csw  = ((lane & 3) ^ ((rowl >> 1) & 3)) << 4;
    boffs[t] = (n0 + rowl) * K + csw;                  // N is multiple of 256
  }

  // fragment read constants: slot s = (kk*2+kh) ^ ((l31>>1)&3)
  const int w2  = (l31 >> 1) & 3;
  const int sA0 = (kh ^ w2) << 4;
  int arow[2], brow[4];
#pragma unroll
  for (int mi = 0; mi < 2; mi++) arow[mi] = (wm + mi * 32 + l31) * 64;
#pragma unroll
  for (int nj = 0; nj < 4; nj++) brow[nj] = (wn + nj * 32 + l31) * 64;

  v16i acc[2][4] = {};
  const int NT = K >> 6;

  // prologue: stage tiles 0,1 into bufs 0,1 (issue order = vmcnt order; 6/tile)
#pragma unroll
  for (int t = 0; t < 2; t++) GLD16(A  + aoffs[t],      &lds[0][ldstA[t]]);
#pragma unroll
  for (int t = 0; t < 4; t++) GLD16(Bm + boffs[t],      &lds[0][ldstB[t]]);
#pragma unroll
  for (int t = 0; t < 2; t++) GLD16(A  + aoffs[t] + 64, &lds[1][ldstA[t]]);
#pragma unroll
  for (int t = 0; t < 4; t++) GLD16(Bm + boffs[t] + 64, &lds[1][ldstB[t]]);

  for (int kt = 0; kt < NT; kt++){
    const int8_t* buf = lds[kt % 3];
    if (kt + 1 < NT) __builtin_amdgcn_s_waitcnt(WAIT_VM6);
    else             __builtin_amdgcn_s_waitcnt(WAIT_VM0);
    __builtin_amdgcn_s_barrier();          // raw: no compiler vmcnt(0) fence
    __builtin_amdgcn_sched_barrier(0);     // nothing (esp. next DMA) crosses up

    v4i af[2][2], bf[2][4];                // [kk][...]
#pragma unroll
    for (int kk = 0; kk < 2; kk++){
      const int sb = sA0 ^ (kk << 5);
#pragma unroll
      for (int mi = 0; mi < 2; mi++)
        af[kk][mi] = *(const v4i*)(buf + arow[mi] + sb);
#pragma unroll
      for (int nj = 0; nj < 4; nj++)
        bf[kk][nj] = *(const v4i*)(buf + 8192 + brow[nj] + sb);
    }

    if (kt + 2 < NT){                      // prefetch distance 2
      int8_t* nbuf = lds[(kt + 2) % 3];
      const int ko = (kt + 2) << 6;
#pragma unroll
      for (int t = 0; t < 2; t++) GLD16(A  + aoffs[t] + ko, nbuf + ldstA[t]);
#pragma unroll
      for (int t = 0; t < 4; t++) GLD16(Bm + boffs[t] + ko, nbuf + ldstB[t]);
    }

#pragma unroll
    for (int kk = 0; kk < 2; kk++)
#pragma unroll
      for (int mi = 0; mi < 2; mi++)
#pragma unroll
        for (int nj = 0; nj < 4; nj++)
          acc[mi][nj] = __builtin_amdgcn_mfma_i32_32x32x32_i8(af[kk][mi], bf[kk][nj], acc[mi][nj], 0, 0, 0);
  }

  // epilogue scalars
  float s_h, off_h;
  if constexpr (MODE == 1){
    float gmin = dec_f(sc[1]), gmax = dec_f(sc[5]);
    float sg = fmaxf(gmax - gmin, 1e-8f) / 255.0f;
    float zp = rintf(-gmin / sg);
    float sw = fmaxf(__uint_as_float(sc[4]), 1e-8f) / 127.0f;
    s_h = sg * sw; off_h = 128.0f - zp;
  } else {
    float xmin = dec_f(sc[0]), xmax = dec_f(sc[2]);
    float sx = fmaxf(xmax - xmin, 1e-8f) / 255.0f;
    float zp = rintf(-xmin / sx);
    float sw = fmaxf(__uint_as_float(sc[3]), 1e-8f) / 127.0f;
    s_h = sx * sw; off_h = 128.0f - zp;
  }
  float qs = 1.0f, qzp = 0.0f;
  if constexpr (MODE == 2){
    float gmin = dec_f(sc[1]), gmax = dec_f(sc[5]);
    qs = fmaxf(gmax - gmin, 1e-8f) / 255.0f;
    qzp = rintf(-gmin / qs);
  }

  // C/D 32x32 layout: col = lane&31, row = (reg&3) + 8*(reg>>2) + 4*(lane>>5)
  float lmin = 3.4e38f, lmax = -3.4e38f;
#pragma unroll
  for (int nj = 0; nj < 4; nj++){
    const int n = n0 + wn + nj * 32 + l31;
    const float rsv = off_h * (float)rowsum[n];
    const float bv = bias[n];
#pragma unroll
    for (int mi = 0; mi < 2; mi++){
      const int mbase = m0 + wm + mi * 32 + 4 * kh;
#pragma unroll
      for (int r = 0; r < 16; r++){
        const int m = mbase + (r & 3) + 8 * (r >> 2);
        if (m < M){
          float h = s_h * ((float)acc[mi][nj][r] + rsv) + bv;
          if constexpr (MODE == 0){
            float gv = int_gelu_f(h);
            lmin = fminf(lmin, gv); lmax = fmaxf(lmax, gv);
          } else if constexpr (MODE == 3){
            float gv = int_gelu_f(h);
            lmin = fminf(lmin, gv); lmax = fmaxf(lmax, gv);
            ((_Float16*)Cout)[(size_t)m * N + n] = (_Float16)gv;
          } else if constexpr (MODE == 2){
            float gv = int_gelu_f(h);
            float qf = fminf(fmaxf(rintf(gv / qs) + qzp, 0.0f), 255.0f);
            ((int8_t*)Cout)[(size_t)m * N + n] = (int8_t)((int)qf - 128);
          } else {
            ((float*)Cout)[(size_t)m * N + n] = h;
          }
        }
      }
    }
  }

  if constexpr (MODE == 0 || MODE == 3){
    __syncthreads();                   // all waves done with LDS -> reuse as scratch
    float* redA = (float*)&lds[0][0];
    float* redB = ((float*)&lds[0][0]) + 256;
    redA[tid] = lmin; redB[tid] = lmax;
    __syncthreads();
    for (int st = 128; st > 0; st >>= 1){
      if (tid < st){
        redA[tid] = fminf(redA[tid], redA[tid + st]);
        redB[tid] = fmaxf(redB[tid], redB[tid + st]);
      }
      __syncthreads();
    }
    if (tid == 0){
      atomicMin(&sc[1], enc_f(redA[0]));
      atomicMax(&sc[5], enc_f(redB[0]));
    }
  }
}

extern "C" void kernel_launch(void* const* d_in, const int* in_sizes, int n_in,
                              void* d_out, int out_size, void* d_ws, size_t ws_size,
                              hipStream_t stream)
{
  const float* x  = (const float*)d_in[0];
  const float* w1 = (const float*)d_in[1];
  const float* b1 = (const float*)d_in[2];
  const float* w2 = (const float*)d_in[3];
  const float* b2 = (const float*)d_in[4];
  float* out = (float*)d_out;

  const int H = in_sizes[2];            // 3072
  const int D = in_sizes[4];            // 768
  const int M = in_sizes[0] / D;        // 12608

  char* ws = (char*)d_ws;
  unsigned* sc = (unsigned*)ws;
  size_t off = 256;
  int8_t* qx  = (int8_t*)(ws + off); off += (size_t)M * D;   // 9.68 MB
  int8_t* qw1 = (int8_t*)(ws + off); off += (size_t)H * D;   // 2.36 MB
  int8_t* qw2 = (int8_t*)(ws + off); off += (size_t)D * H;   // 2.36 MB
  int* rs1 = (int*)(ws + off); off += (size_t)H * 4;
  int* rs2 = (int*)(ws + off); off += 4096;
  int8_t* qg  = (int8_t*)(ws + off); off += (size_t)M * H;   // 38.7 MB
  _Float16* g16 = (_Float16*)(ws + off);                      // 77.5 MB (big path)
  const size_t need_big = off + (size_t)M * H * 2;
  (void)n_in; (void)out_size;

  // scalar init: slots 0,1 = 0xFFFFFFFF (encoded +inf for min); 2..5 = 0
  hipMemsetAsync(sc, 0xFF, 8, stream);
  hipMemsetAsync(sc + 2, 0x00, 16, stream);

  reduce_stats<<<dim3(1280), dim3(256), 0, stream>>>(
      (const float4*)x, M * D / 4,
      (const float4*)w1, H * D / 4,
      (const float4*)w2, D * H / 4, sc);

  quant_all<<<dim3(2048 + H + D), dim3(256), 0, stream>>>(
      (const float4*)x, (unsigned*)qx, (long)M * D / 4,
      w1, w2, qw1, qw2, rs1, rs2, sc, H, D);

  const dim3 g1(H / 256, (M + 127) / 128), g2(D / 256, (M + 127) / 128), blk(256);

  if (ws_size >= need_big){
    // GEMM1 (single pass): g stats + store g fp16
    gemm_i8<3><<<g1, blk, 0, stream>>>(qx, qw1, rs1, b1, g16, M, H, D, sc);
    // elementwise quantize g -> qg
    quant_g<<<dim3(2048), blk, 0, stream>>>(
        (const vh8*)g16, (uint2*)qg, (long)M * H / 8, sc);
  } else {
    // fallback: exact 2-pass GEMM1 (stats, then quantize)
    gemm_i8<0><<<g1, blk, 0, stream>>>(qx, qw1, rs1, b1, nullptr, M, H, D, sc);
    gemm_i8<2><<<g1, blk, 0, stream>>>(qx, qw1, rs1, b1, qg, M, H, D, sc);
  }

  // GEMM2: out = qg @ qw2^T + b2
  gemm_i8<1><<<g2, blk, 0, stream>>>(qg, qw2, rs2, b2, out, M, D, H, sc);
}

// Round 2
// 329.800 us; speedup vs baseline: 1.0060x; 1.0060x over previous
//
#include <hip/hip_runtime.h>
#include <stdint.h>
#include <stddef.h>

typedef int v4i  __attribute__((ext_vector_type(4)));
typedef int v16i __attribute__((ext_vector_type(16)));
typedef _Float16 vh8 __attribute__((ext_vector_type(8)));

#define GELU_A   (-0.2888f)
#define GELU_B   (-1.769f)
#define INV_SQRT2 0.70710678118654752440f

// async 16B global->LDS (lane i's 16B lands at ldsbase + i*16; ldsbase wave-uniform)
#define GLD16(gp, lp) __builtin_amdgcn_global_load_lds( \
    (const __attribute__((address_space(1))) unsigned int*)(gp), \
    (__attribute__((address_space(3))) unsigned int*)(lp), 16, 0, 0)

// gfx9 s_waitcnt imm: vmcnt[3:0]=bits3:0, expcnt=bits6:4, lgkmcnt=bits11:8, vmcnt[5:4]=bits15:14
#define WAIT_VM4   0x0F74   // vmcnt(4),  lgkm free
#define WAIT_VM3   0x0F73   // vmcnt(3),  lgkm free
#define WAIT_VM0   0x0F70   // vmcnt(0),  lgkm free
#define WAIT_LGKM0 0xC07F   // lgkmcnt(0), vmcnt free (=63)

// scalar slots: sc[0]=enc(xmin) sc[1]=enc(gmin)  [init 0xFFFFFFFF]
//               sc[2]=enc(xmax) sc[3]=|w1|max bits sc[4]=|w2|max bits sc[5]=enc(gmax) [init 0]

__device__ __forceinline__ unsigned enc_f(float f){
  unsigned u = __float_as_uint(f);
  return (u & 0x80000000u) ? ~u : (u | 0x80000000u);
}
__device__ __forceinline__ float dec_f(unsigned e){
  unsigned u = (e & 0x80000000u) ? (e & 0x7FFFFFFFu) : ~e;
  return __uint_as_float(u);
}

__device__ __forceinline__ float int_gelu_f(float x){
  float t = x * INV_SQRT2;
  float at = fminf(fabsf(t), 1.769f);
  float u = at + GELU_B;                 // in [-1.769, 0]
  float p = GELU_A * (u * u) + 1.0f;
  float L = (t > 0.0f) ? p : ((t < 0.0f) ? -p : 0.0f);
  return x * 0.5f * (1.0f + L);
}

// blocks [0,1024): x min/max; [1024,1152): absmax w1 -> sc[3]; [1152,1280): absmax w2 -> sc[4]
__global__ __launch_bounds__(256) void reduce_stats(
    const float4* __restrict__ x, int nx4,
    const float4* __restrict__ w1, int n14,
    const float4* __restrict__ w2, int n24,
    unsigned* __restrict__ sc)
{
  __shared__ float ra[256], rb[256];
  const int tid = threadIdx.x;
  const int b = blockIdx.x;
  if (b < 1024){
    float lmin = 3.4e38f, lmax = -3.4e38f;
    for (long i = (long)b * 256 + tid; i < nx4; i += 1024L * 256L){
      float4 v = x[i];
      lmin = fminf(lmin, fminf(fminf(v.x, v.y), fminf(v.z, v.w)));
      lmax = fmaxf(lmax, fmaxf(fmaxf(v.x, v.y), fmaxf(v.z, v.w)));
    }
    ra[tid] = lmin; rb[tid] = lmax;
    __syncthreads();
    for (int s = 128; s > 0; s >>= 1){
      if (tid < s){ ra[tid] = fminf(ra[tid], ra[tid + s]); rb[tid] = fmaxf(rb[tid], rb[tid + s]); }
      __syncthreads();
    }
    if (tid == 0){
      atomicMin(&sc[0], enc_f(ra[0]));
      atomicMax(&sc[2], enc_f(rb[0]));
    }
  } else {
    const float4* w; int n4; int slot; int bl;
    if (b < 1152){ w = w1; n4 = n14; slot = 3; bl = b - 1024; }
    else         { w = w2; n4 = n24; slot = 4; bl = b - 1152; }
    float la = 0.0f;
    for (long i = (long)bl * 256 + tid; i < n4; i += 128L * 256L){
      float4 v = w[i];
      la = fmaxf(la, fmaxf(fmaxf(fabsf(v.x), fabsf(v.y)), fmaxf(fabsf(v.z), fabsf(v.w))));
    }
    ra[tid] = la;
    __syncthreads();
    for (int s = 128; s > 0; s >>= 1){
      if (tid < s) ra[tid] = fmaxf(ra[tid], ra[tid + s]);
      __syncthreads();
    }
    if (tid == 0) atomicMax(&sc[slot], __float_as_uint(ra[0]));
  }
}

// fused: blocks [0,2048) act-quant x -> qx ((q-128) int8, packed u32);
//        blocks [2048, 2048+H+D) weight-quant rows (+row sums)
__global__ __launch_bounds__(256) void quant_all(
    const float4* __restrict__ x, unsigned* __restrict__ qx, long nx4,
    const float* __restrict__ w1, const float* __restrict__ w2,
    int8_t* __restrict__ qw1, int8_t* __restrict__ qw2,
    int* __restrict__ rs1, int* __restrict__ rs2,
    const unsigned* __restrict__ sc, int H, int D)
{
  const int tid = threadIdx.x;
  const int b = blockIdx.x;
  if (b < 2048){
    const float vmin = dec_f(sc[0]);
    const float vmax = dec_f(sc[2]);
    const float s  = fmaxf(vmax - vmin, 1e-8f) / 255.0f;
    const float zp = rintf(-vmin / s);
    for (long i = (long)b * 256 + tid; i < nx4; i += 2048L * 256L){
      float4 v = x[i];
      int q0 = (int)fminf(fmaxf(rintf(v.x / s) + zp, 0.0f), 255.0f) - 128;
      int q1 = (int)fminf(fmaxf(rintf(v.y / s) + zp, 0.0f), 255.0f) - 128;
      int q2 = (int)fminf(fmaxf(rintf(v.z / s) + zp, 0.0f), 255.0f) - 128;
      int q3 = (int)fminf(fmaxf(rintf(v.w / s) + zp, 0.0f), 255.0f) - 128;
      qx[i] = ((unsigned)(q0 & 255)) | ((unsigned)(q1 & 255) << 8) |
              ((unsigned)(q2 & 255) << 16) | ((unsigned)(q3 & 255) << 24);
    }
  } else {
    __shared__ int red[256];
    const int wb = b - 2048;
    const float* w; int8_t* q; int* rs; int K; int n; float s;
    if (wb < H){ w = w1; q = qw1; rs = rs1; K = D; n = wb;
                 s = fmaxf(__uint_as_float(sc[3]), 1e-8f) / 127.0f; }
    else       { w = w2; q = qw2; rs = rs2; K = H; n = wb - H;
                 s = fmaxf(__uint_as_float(sc[4]), 1e-8f) / 127.0f; }
    int sum = 0;
    for (int k = tid; k < K; k += 256){
      float v = w[(size_t)n * K + k];
      float qf = fminf(fmaxf(rintf(v / s), -128.0f), 127.0f);
      int qi = (int)qf;
      q[(size_t)n * K + k] = (int8_t)qi;
      sum += qi;
    }
    red[tid] = sum;
    __syncthreads();
    for (int st = 128; st > 0; st >>= 1){
      if (tid < st) red[tid] += red[tid + st];
      __syncthreads();
    }
    if (tid == 0) rs[n] = red[0];
  }
}

// elementwise: fp16 g -> int8 qg ((q-128)), using g stats
__global__ __launch_bounds__(256) void quant_g(
    const vh8* __restrict__ g, uint2* __restrict__ qg, long n8,
    const unsigned* __restrict__ sc)
{
  const float gmin = dec_f(sc[1]), gmax = dec_f(sc[5]);
  const float qs  = fmaxf(gmax - gmin, 1e-8f) / 255.0f;
  const float qzp = rintf(-gmin / qs);
  const long stride = (long)gridDim.x * blockDim.x;
  for (long i = (long)blockIdx.x * blockDim.x + threadIdx.x; i < n8; i += stride){
    vh8 v = g[i];
    unsigned lo = 0, hi = 0;
#pragma unroll
    for (int j = 0; j < 4; j++){
      int q = (int)fminf(fmaxf(rintf((float)v[j] / qs) + qzp, 0.0f), 255.0f) - 128;
      lo |= ((unsigned)(q & 255)) << (8 * j);
    }
#pragma unroll
    for (int j = 0; j < 4; j++){
      int q = (int)fminf(fmaxf(rintf((float)v[4 + j] / qs) + qzp, 0.0f), 255.0f) - 128;
      hi |= ((unsigned)(q & 255)) << (8 * j);
    }
    uint2 o; o.x = lo; o.y = hi;
    qg[i] = o;
  }
}

// MODE 0: h->gelu-> g min/max atomics only (no store)          [fallback pass A]
// MODE 3: h->gelu-> store g fp16 + g min/max atomics            [main pass A]
// MODE 2: h->gelu-> quantize with g stats -> store int8 (q-128) [fallback pass B]
// MODE 1: h + bias -> store fp32 out                            [GEMM2]
//
// 8-phase-style schedule (T3+T4+T5) ported to i8, BM=256 x BN, BK=64,
// mfma_i32_32x32x32_i8, 8 waves (512 thr) as (BM/WM)x(BN/WN) grid.
// 3 LDS buffers (prefetch distance 2 => ~2 K-tile latency budget).
// Per K-tile: 2 phases (one per 32-wide k-half). Phase =
//   { ds_read frags ; issue stage glds (tile kt+2) ; [vmcnt counted, phase 1 only]
//     ; s_barrier ; lgkmcnt(0) ; setprio(1) MFMAs setprio(0) ; s_barrier }.
// vmcnt is NEVER 0 in steady state: waits tile kt+1's loads, leaves kt+2's in
// flight across the barrier. Race-freedom: DMA into buf b issues >=1 barrier
// after buf b's reads (tile kt-1) were lgkm-drained (3-buffer rotation).
template<int MODE, int BM, int BN, int WM, int WN>
__global__ __launch_bounds__(512) void gemm_i8(
    const int8_t* __restrict__ A, const int8_t* __restrict__ Bm,
    const int* __restrict__ rowsum, const float* __restrict__ bias,
    void* __restrict__ Cout, int M, int N, int K,
    unsigned* __restrict__ sc)
{
  constexpr int NWN  = BN / WN;          // waves along N
  constexpr int MI   = WM / 32;          // A frags per wave
  constexpr int NJ   = WN / 32;          // B frags per wave
  constexpr int NBG  = BN / 128;         // B stage-glds per wave per tile (A is 2)
  constexpr int LDSB = 16384 + BN * 64;  // bytes per buffer (A 16K + B)
  constexpr int WAIT_STEADY = (NBG == 2) ? WAIT_VM4 : WAIT_VM3;  // vmcnt(2+NBG)
  __shared__ __align__(16) int8_t lds[3][LDSB];

  const int tid  = threadIdx.x;
  const int lane = tid & 63;
  const int wave = tid >> 6;             // 0..7
  const int l31  = lane & 31;
  const int kh   = lane >> 5;            // which 16B half of a 32-k block
  const int n0   = blockIdx.x * BN;
  const int m0   = blockIdx.y * BM;
  const int wm   = (wave / NWN) * WM;
  const int wn   = (wave % NWN) * WN;

  // staging: A tile 256x64 -> 16 glds (2/wave); B tile BNx64 -> 2*NBG... NBG/wave.
  // lane L -> row rbase+(L>>2), LDS chunk L&3, src chunk (L&3)^((row>>1)&3).
  int aoffs[2], boffs[NBG];
  const int ldstA[2] = { wave * 2048, wave * 2048 + 1024 };
  int ldstB[NBG];
#pragma unroll
  for (int t = 0; t < 2; t++){
    int rowl = wave * 32 + t * 16 + (lane >> 2);       // 0..255
    int csw  = ((lane & 3) ^ ((rowl >> 1) & 3)) << 4;  // swizzled source chunk
    int ga = m0 + rowl; if (ga >= M) ga = M - 1;
    aoffs[t] = ga * K + csw;
  }
#pragma unroll
  for (int t = 0; t < NBG; t++){
    int rowl = wave * 16 * NBG + t * 16 + (lane >> 2); // 0..BN-1
    int csw  = ((lane & 3) ^ ((rowl >> 1) & 3)) << 4;
    boffs[t] = (n0 + rowl) * K + csw;                  // N multiple of BN
    ldstB[t] = 16384 + wave * NBG * 1024 + t * 1024;
  }

  // fragment read constants: phys chunk = (kk*2+kh) ^ ((l31>>1)&3)
  const int w2  = (l31 >> 1) & 3;
  const int sA0 = (kh ^ w2) << 4;
  int arow[MI], brow[NJ];
#pragma unroll
  for (int mi = 0; mi < MI; mi++) arow[mi] = (wm + mi * 32 + l31) * 64;
#pragma unroll
  for (int nj = 0; nj < NJ; nj++) brow[nj] = 16384 + (wn + nj * 32 + l31) * 64;

  v16i acc[MI][NJ] = {};
  const int NT = K >> 6;

  // prologue: stage tiles 0,1 into bufs 0,1; per-wave issue order matters.
#pragma unroll
  for (int bt = 0; bt < 2; bt++){
#pragma unroll
    for (int t = 0; t < 2;   t++) GLD16(A  + aoffs[t] + bt * 64, &lds[bt][ldstA[t]]);
#pragma unroll
    for (int t = 0; t < NBG; t++) GLD16(Bm + boffs[t] + bt * 64, &lds[bt][ldstB[t]]);
  }
  __builtin_amdgcn_s_waitcnt(WAIT_STEADY);   // tile0's 2+NBG done; tile1's in flight
  __builtin_amdgcn_s_barrier();

  int bcur = 0, bst = 2;
  for (int kt = 0; kt < NT; kt++){
    const int8_t* buf = &lds[bcur][0];
    int8_t* nbuf = &lds[bst][0];
    const bool pf = (kt + 2 < NT);
    const int ko = (kt + 2) << 6;

    v4i af[MI], bf[NJ];

    // ---------------- phase 0 (kk = 0) ----------------
#pragma unroll
    for (int mi = 0; mi < MI; mi++) af[mi] = *(const v4i*)(buf + arow[mi] + sA0);
#pragma unroll
    for (int nj = 0; nj < NJ; nj++) bf[nj] = *(const v4i*)(buf + brow[nj] + sA0);
    if (pf){
#pragma unroll
      for (int t = 0; t < 2; t++) GLD16(A + aoffs[t] + ko, nbuf + ldstA[t]);
    }
    __builtin_amdgcn_sched_barrier(0);
    __builtin_amdgcn_s_barrier();
    __builtin_amdgcn_s_waitcnt(WAIT_LGKM0);
    __builtin_amdgcn_sched_barrier(0);
    __builtin_amdgcn_s_setprio(1);
#pragma unroll
    for (int mi = 0; mi < MI; mi++)
#pragma unroll
      for (int nj = 0; nj < NJ; nj++)
        acc[mi][nj] = __builtin_amdgcn_mfma_i32_32x32x32_i8(af[mi], bf[nj], acc[mi][nj], 0, 0, 0);
    __builtin_amdgcn_s_setprio(0);
    __builtin_amdgcn_sched_barrier(0);
    __builtin_amdgcn_s_barrier();

    // ---------------- phase 1 (kk = 1) ----------------
#pragma unroll
    for (int mi = 0; mi < MI; mi++) af[mi] = *(const v4i*)(buf + arow[mi] + (sA0 ^ 32));
#pragma unroll
    for (int nj = 0; nj < NJ; nj++) bf[nj] = *(const v4i*)(buf + brow[nj] + (sA0 ^ 32));
    if (pf){
#pragma unroll
      for (int t = 0; t < NBG; t++) GLD16(Bm + boffs[t] + ko, nbuf + ldstB[t]);
    }
    __builtin_amdgcn_sched_barrier(0);
    if (pf) __builtin_amdgcn_s_waitcnt(WAIT_STEADY); // tile kt+1 staged; kt+2 in flight
    else    __builtin_amdgcn_s_waitcnt(WAIT_VM0);    // tail: drain everything
    __builtin_amdgcn_s_barrier();
    __builtin_amdgcn_s_waitcnt(WAIT_LGKM0);
    __builtin_amdgcn_sched_barrier(0);
    __builtin_amdgcn_s_setprio(1);
#pragma unroll
    for (int mi = 0; mi < MI; mi++)
#pragma unroll
      for (int nj = 0; nj < NJ; nj++)
        acc[mi][nj] = __builtin_amdgcn_mfma_i32_32x32x32_i8(af[mi], bf[nj], acc[mi][nj], 0, 0, 0);
    __builtin_amdgcn_s_setprio(0);
    __builtin_amdgcn_sched_barrier(0);
    __builtin_amdgcn_s_barrier();

    bcur = (bcur == 2) ? 0 : bcur + 1;
    bst  = (bst  == 2) ? 0 : bst  + 1;
  }

  // epilogue scalars
  float s_h, off_h;
  if constexpr (MODE == 1){
    float gmin = dec_f(sc[1]), gmax = dec_f(sc[5]);
    float sg = fmaxf(gmax - gmin, 1e-8f) / 255.0f;
    float zp = rintf(-gmin / sg);
    float sw = fmaxf(__uint_as_float(sc[4]), 1e-8f) / 127.0f;
    s_h = sg * sw; off_h = 128.0f - zp;
  } else {
    float xmin = dec_f(sc[0]), xmax = dec_f(sc[2]);
    float sx = fmaxf(xmax - xmin, 1e-8f) / 255.0f;
    float zp = rintf(-xmin / sx);
    float sw = fmaxf(__uint_as_float(sc[3]), 1e-8f) / 127.0f;
    s_h = sx * sw; off_h = 128.0f - zp;
  }
  float qs = 1.0f, qzp = 0.0f;
  if constexpr (MODE == 2){
    float gmin = dec_f(sc[1]), gmax = dec_f(sc[5]);
    qs = fmaxf(gmax - gmin, 1e-8f) / 255.0f;
    qzp = rintf(-gmin / qs);
  }

  // C/D 32x32 layout: col = lane&31, row = (reg&3) + 8*(reg>>2) + 4*(lane>>5)
  float lmin = 3.4e38f, lmax = -3.4e38f;
#pragma unroll
  for (int nj = 0; nj < NJ; nj++){
    const int n = n0 + wn + nj * 32 + l31;
    const float rsv = off_h * (float)rowsum[n];
    const float bv = bias[n];
#pragma unroll
    for (int mi = 0; mi < MI; mi++){
      const int mbase = m0 + wm + mi * 32 + 4 * kh;
#pragma unroll
      for (int r = 0; r < 16; r++){
        const int m = mbase + (r & 3) + 8 * (r >> 2);
        if (m < M){
          float h = s_h * ((float)acc[mi][nj][r] + rsv) + bv;
          if constexpr (MODE == 0){
            float gv = int_gelu_f(h);
            lmin = fminf(lmin, gv); lmax = fmaxf(lmax, gv);
          } else if constexpr (MODE == 3){
            float gv = int_gelu_f(h);
            lmin = fminf(lmin, gv); lmax = fmaxf(lmax, gv);
            ((_Float16*)Cout)[(size_t)m * N + n] = (_Float16)gv;
          } else if constexpr (MODE == 2){
            float gv = int_gelu_f(h);
            float qf = fminf(fmaxf(rintf(gv / qs) + qzp, 0.0f), 255.0f);
            ((int8_t*)Cout)[(size_t)m * N + n] = (int8_t)((int)qf - 128);
          } else {
            ((float*)Cout)[(size_t)m * N + n] = h;
          }
        }
      }
    }
  }

  if constexpr (MODE == 0 || MODE == 3){
    __syncthreads();                   // all waves done with LDS -> reuse as scratch
    float* redA = (float*)&lds[0][0];
    float* redB = ((float*)&lds[0][0]) + 512;
    redA[tid] = lmin; redB[tid] = lmax;
    __syncthreads();
    for (int st = 256; st > 0; st >>= 1){
      if (tid < st){
        redA[tid] = fminf(redA[tid], redA[tid + st]);
        redB[tid] = fmaxf(redB[tid], redB[tid + st]);
      }
      __syncthreads();
    }
    if (tid == 0){
      atomicMin(&sc[1], enc_f(redA[0]));
      atomicMax(&sc[5], enc_f(redB[0]));
    }
  }
}

extern "C" void kernel_launch(void* const* d_in, const int* in_sizes, int n_in,
                              void* d_out, int out_size, void* d_ws, size_t ws_size,
                              hipStream_t stream)
{
  const float* x  = (const float*)d_in[0];
  const float* w1 = (const float*)d_in[1];
  const float* b1 = (const float*)d_in[2];
  const float* w2 = (const float*)d_in[3];
  const float* b2 = (const float*)d_in[4];
  float* out = (float*)d_out;

  const int H = in_sizes[2];            // 3072
  const int D = in_sizes[4];            // 768
  const int M = in_sizes[0] / D;        // 12608

  char* ws = (char*)d_ws;
  unsigned* sc = (unsigned*)ws;
  size_t off = 256;
  int8_t* qx  = (int8_t*)(ws + off); off += (size_t)M * D;   // 9.68 MB
  int8_t* qw1 = (int8_t*)(ws + off); off += (size_t)H * D;   // 2.36 MB
  int8_t* qw2 = (int8_t*)(ws + off); off += (size_t)D * H;   // 2.36 MB
  int* rs1 = (int*)(ws + off); off += (size_t)H * 4;
  int* rs2 = (int*)(ws + off); off += 4096;
  int8_t* qg  = (int8_t*)(ws + off); off += (size_t)M * H;   // 38.7 MB
  _Float16* g16 = (_Float16*)(ws + off);                      // 77.5 MB (big path)
  const size_t need_big = off + (size_t)M * H * 2;
  (void)n_in; (void)out_size;

  // scalar init: slots 0,1 = 0xFFFFFFFF (encoded +inf for min); 2..5 = 0
  hipMemsetAsync(sc, 0xFF, 8, stream);
  hipMemsetAsync(sc + 2, 0x00, 16, stream);

  reduce_stats<<<dim3(1280), dim3(256), 0, stream>>>(
      (const float4*)x, M * D / 4,
      (const float4*)w1, H * D / 4,
      (const float4*)w2, D * H / 4, sc);

  quant_all<<<dim3(2048 + H + D), dim3(256), 0, stream>>>(
      (const float4*)x, (unsigned*)qx, (long)M * D / 4,
      w1, w2, qw1, qw2, rs1, rs2, sc, H, D);

  // GEMM1: 256x256 tile, waves 2Mx4N (wave 128x64). grid (12, 50).
  // GEMM2: 256x128 tile, waves 4Mx2N (wave 64x64).  grid (6, 50).
  const dim3 g1(H / 256, (M + 255) / 256), g2(D / 128, (M + 255) / 256), blk(512);

  if (ws_size >= need_big){
    // GEMM1 (single pass): g stats + store g fp16
    gemm_i8<3, 256, 256, 128, 64><<<g1, blk, 0, stream>>>(qx, qw1, rs1, b1, g16, M, H, D, sc);
    // elementwise quantize g -> qg
    quant_g<<<dim3(2048), dim3(256), 0, stream>>>(
        (const vh8*)g16, (uint2*)qg, (long)M * H / 8, sc);
  } else {
    // fallback: exact 2-pass GEMM1 (stats, then quantize)
    gemm_i8<0, 256, 256, 128, 64><<<g1, blk, 0, stream>>>(qx, qw1, rs1, b1, nullptr, M, H, D, sc);
    gemm_i8<2, 256, 256, 128, 64><<<g1, blk, 0, stream>>>(qx, qw1, rs1, b1, qg, M, H, D, sc);
  }

  // GEMM2: out = qg @ qw2^T + b2
  gemm_i8<1, 256, 128, 64, 64><<<g2, blk, 0, stream>>>(qg, qw2, rs2, b2, out, M, D, H, sc);
}

// Round 3
// 327.732 us; speedup vs baseline: 1.0123x; 1.0063x over previous
//
#include <hip/hip_runtime.h>
#include <stdint.h>
#include <stddef.h>

typedef int v4i  __attribute__((ext_vector_type(4)));
typedef int v16i __attribute__((ext_vector_type(16)));
typedef _Float16 vh8 __attribute__((ext_vector_type(8)));

#define GELU_A   (-0.2888f)
#define GELU_B   (-1.769f)
#define INV_SQRT2 0.70710678118654752440f

// ---------------------------------------------------------------------------
// Fragment ("flatmm") layout: operand stored as [rows/32][K/32][1024B] where
// byte (lane*16 + j) of frag (rb,kb) = W[rb*32 + (lane&31)][kb*32 + (lane>>5)*16 + j].
// This is byte-identical to what the verified LDS kernel fed mfma_i32_32x32x32_i8,
// so a wave's frag load is ONE coalesced global_load_dwordx4 (1KB) -> VGPRs.
// GEMM then needs no LDS and no barriers at all.
// ---------------------------------------------------------------------------

// scalar slots: sc[0]=enc(xmin) sc[1]=enc(gmin)  [init 0xFFFFFFFF]
//               sc[2]=enc(xmax) sc[3]=|w1|max bits sc[4]=|w2|max bits sc[5]=enc(gmax) [init 0]

__device__ __forceinline__ unsigned enc_f(float f){
  unsigned u = __float_as_uint(f);
  return (u & 0x80000000u) ? ~u : (u | 0x80000000u);
}
__device__ __forceinline__ float dec_f(unsigned e){
  unsigned u = (e & 0x80000000u) ? (e & 0x7FFFFFFFu) : ~e;
  return __uint_as_float(u);
}

__device__ __forceinline__ float int_gelu_f(float x){
  float t = x * INV_SQRT2;
  float at = fminf(fabsf(t), 1.769f);
  float u = at + GELU_B;                 // in [-1.769, 0]
  float p = GELU_A * (u * u) + 1.0f;
  float L = (t > 0.0f) ? p : ((t < 0.0f) ? -p : 0.0f);
  return x * 0.5f * (1.0f + L);
}

// blocks [0,1024): x min/max; [1024,1152): absmax w1 -> sc[3]; [1152,1280): absmax w2 -> sc[4]
__global__ __launch_bounds__(256) void reduce_stats(
    const float4* __restrict__ x, int nx4,
    const float4* __restrict__ w1, int n14,
    const float4* __restrict__ w2, int n24,
    unsigned* __restrict__ sc)
{
  __shared__ float ra[256], rb[256];
  const int tid = threadIdx.x;
  const int b = blockIdx.x;
  if (b < 1024){
    float lmin = 3.4e38f, lmax = -3.4e38f;
    for (long i = (long)b * 256 + tid; i < nx4; i += 1024L * 256L){
      float4 v = x[i];
      lmin = fminf(lmin, fminf(fminf(v.x, v.y), fminf(v.z, v.w)));
      lmax = fmaxf(lmax, fmaxf(fmaxf(v.x, v.y), fmaxf(v.z, v.w)));
    }
    ra[tid] = lmin; rb[tid] = lmax;
    __syncthreads();
    for (int s = 128; s > 0; s >>= 1){
      if (tid < s){ ra[tid] = fminf(ra[tid], ra[tid + s]); rb[tid] = fmaxf(rb[tid], rb[tid + s]); }
      __syncthreads();
    }
    if (tid == 0){
      atomicMin(&sc[0], enc_f(ra[0]));
      atomicMax(&sc[2], enc_f(rb[0]));
    }
  } else {
    const float4* w; int n4; int slot; int bl;
    if (b < 1152){ w = w1; n4 = n14; slot = 3; bl = b - 1024; }
    else         { w = w2; n4 = n24; slot = 4; bl = b - 1152; }
    float la = 0.0f;
    for (long i = (long)bl * 256 + tid; i < n4; i += 128L * 256L){
      float4 v = w[i];
      la = fmaxf(la, fmaxf(fmaxf(fabsf(v.x), fabsf(v.y)), fmaxf(fabsf(v.z), fabsf(v.w))));
    }
    ra[tid] = la;
    __syncthreads();
    for (int s = 128; s > 0; s >>= 1){
      if (tid < s) ra[tid] = fmaxf(ra[tid], ra[tid + s]);
      __syncthreads();
    }
    if (tid == 0) atomicMax(&sc[slot], __float_as_uint(ra[0]));
  }
}

// quantize 4 floats -> 4 packed uint8 (asym act quant, stored as (q-128))
__device__ __forceinline__ unsigned quant4_act(float4 v, float s, float zp){
  int q0 = (int)fminf(fmaxf(rintf(v.x / s) + zp, 0.0f), 255.0f) - 128;
  int q1 = (int)fminf(fmaxf(rintf(v.y / s) + zp, 0.0f), 255.0f) - 128;
  int q2 = (int)fminf(fmaxf(rintf(v.z / s) + zp, 0.0f), 255.0f) - 128;
  int q3 = (int)fminf(fmaxf(rintf(v.w / s) + zp, 0.0f), 255.0f) - 128;
  return ((unsigned)(q0 & 255)) | ((unsigned)(q1 & 255) << 8) |
         ((unsigned)(q2 & 255) << 16) | ((unsigned)(q3 & 255) << 24);
}

// fused: blocks [0,2048): act-quant x -> qx FRAGMENTED;
//        blocks [2048, 2048+H+D): weight-quant rows -> qw FRAGMENTED (+row sums)
__global__ __launch_bounds__(256) void quant_all(
    const float* __restrict__ x, int8_t* __restrict__ qx, long nchunk,
    const float* __restrict__ w1, const float* __restrict__ w2,
    int8_t* __restrict__ qw1, int8_t* __restrict__ qw2,
    int* __restrict__ rs1, int* __restrict__ rs2,
    const unsigned* __restrict__ sc, int H, int D)
{
  const int tid = threadIdx.x;
  const int b = blockIdx.x;
  if (b < 2048){
    // x: one chunk = 16 consecutive d of one row m -> one 16B frag write
    const float vmin = dec_f(sc[0]);
    const float vmax = dec_f(sc[2]);
    const float s  = fmaxf(vmax - vmin, 1e-8f) / 255.0f;
    const float zp = rintf(-vmin / s);
    const long CPR = (long)(D >> 4);        // chunks per row
    const long KB  = (long)(D >> 5);        // frag K-blocks per row
    for (long i = (long)b * 256 + tid; i < nchunk; i += 2048L * 256L){
      long m = i / CPR; int c = (int)(i - m * CPR);
      const float4* xp = (const float4*)(x + m * (long)D + (long)c * 16);
      uint4 o;
      o.x = quant4_act(xp[0], s, zp);
      o.y = quant4_act(xp[1], s, zp);
      o.z = quant4_act(xp[2], s, zp);
      o.w = quant4_act(xp[3], s, zp);
      size_t off = ((((size_t)(m >> 5)) * KB + (c >> 1)) << 10)
                 + ((size_t)(c & 1) << 9) + ((m & 31) << 4);
      *(uint4*)(qx + off) = o;
    }
  } else {
    __shared__ int red[256];
    const int wb = b - 2048;
    const float* w; int8_t* q; int* rs; int K; int n; float s;
    if (wb < H){ w = w1; q = qw1; rs = rs1; K = D; n = wb;
                 s = fmaxf(__uint_as_float(sc[3]), 1e-8f) / 127.0f; }
    else       { w = w2; q = qw2; rs = rs2; K = H; n = wb - H;
                 s = fmaxf(__uint_as_float(sc[4]), 1e-8f) / 127.0f; }
    int sum = 0;
    const int c = tid;                       // chunk of 16 k (K/16 <= 192 < 256)
    if (c < (K >> 4)){
      const float4* wp = (const float4*)(w + (size_t)n * K + (size_t)c * 16);
      uint4 o; unsigned wds[4];
#pragma unroll
      for (int q4 = 0; q4 < 4; q4++){
        float4 v = wp[q4];
        int qa = (int)fminf(fmaxf(rintf(v.x / s), -128.0f), 127.0f);
        int qb = (int)fminf(fmaxf(rintf(v.y / s), -128.0f), 127.0f);
        int qc = (int)fminf(fmaxf(rintf(v.z / s), -128.0f), 127.0f);
        int qd = (int)fminf(fmaxf(rintf(v.w / s), -128.0f), 127.0f);
        sum += qa + qb + qc + qd;
        wds[q4] = ((unsigned)(qa & 255)) | ((unsigned)(qb & 255) << 8) |
                  ((unsigned)(qc & 255) << 16) | ((unsigned)(qd & 255) << 24);
      }
      o.x = wds[0]; o.y = wds[1]; o.z = wds[2]; o.w = wds[3];
      size_t off = ((((size_t)(n >> 5)) * (K >> 5) + (c >> 1)) << 10)
                 + ((size_t)(c & 1) << 9) + ((n & 31) << 4);
      *(uint4*)(q + off) = o;
    }
    red[tid] = sum;
    __syncthreads();
    for (int st = 128; st > 0; st >>= 1){
      if (tid < st) red[tid] += red[tid + st];
      __syncthreads();
    }
    if (tid == 0) rs[n] = red[0];
  }
}

// g (fragmented fp16, written by GEMM1) -> qg (fragmented int8, (q-128)).
// Pure 2:1 recode: out-chunk i (16B) = quantize(gf bytes [32i, 32i+32)).
__global__ __launch_bounds__(256) void quant_g(
    const vh8* __restrict__ gf, uint4* __restrict__ qg, long nchunk,
    const unsigned* __restrict__ sc)
{
  const float gmin = dec_f(sc[1]), gmax = dec_f(sc[5]);
  const float qs  = fmaxf(gmax - gmin, 1e-8f) / 255.0f;
  const float qzp = rintf(-gmin / qs);
  const long stride = (long)gridDim.x * blockDim.x;
  for (long i = (long)blockIdx.x * blockDim.x + threadIdx.x; i < nchunk; i += stride){
    vh8 v0 = gf[2 * i], v1 = gf[2 * i + 1];
    unsigned wds[4] = {0u, 0u, 0u, 0u};
#pragma unroll
    for (int j = 0; j < 8; j++){
      int q = (int)fminf(fmaxf(rintf((float)v0[j] / qs) + qzp, 0.0f), 255.0f) - 128;
      wds[j >> 2] |= ((unsigned)(q & 255)) << (8 * (j & 3));
    }
#pragma unroll
    for (int j = 0; j < 8; j++){
      int q = (int)fminf(fmaxf(rintf((float)v1[j] / qs) + qzp, 0.0f), 255.0f) - 128;
      wds[2 + (j >> 2)] |= ((unsigned)(q & 255)) << (8 * (j & 3));
    }
    uint4 o; o.x = wds[0]; o.y = wds[1]; o.z = wds[2]; o.w = wds[3];
    qg[i] = o;
  }
}

// Flat (LDS-free, barrier-free) int8 GEMM on pre-fragmented operands.
// MODE 0: h->gelu-> g min/max atomics only (no store)            [fallback pass A]
// MODE 3: h->gelu-> store g fp16 FRAGMENTED + g min/max atomics  [main pass A]
// MODE 2: h->gelu-> quantize -> store int8 FRAGMENTED (q-128)    [fallback pass B]
// MODE 1: h + bias -> store fp32 out LINEAR                      [GEMM2]
//
// 128x128 tile, 4 waves (2Mx2N) of 64x64, mfma_i32_32x32x32_i8, K-step 32.
// Each frag load = 1 coalesced global_load_dwordx4/wave from L2/L3-resident
// pre-fragmented buffers. Ping-pong register prefetch (distance 1); latency
// hidden by 4 waves/SIMD (no barriers => waves drift freely).
template<int MODE>
__global__ __launch_bounds__(256, 4) void gemm_i8f(
    const int8_t* __restrict__ Af, const int8_t* __restrict__ Bf,
    const int* __restrict__ rowsum, const float* __restrict__ bias,
    void* __restrict__ Cout, int M, int N, int K,
    unsigned* __restrict__ sc)
{
  const int tid  = threadIdx.x;
  const int lane = tid & 63;
  const int wave = tid >> 6;
  const int l31  = lane & 31;
  const int kh   = lane >> 5;
  const int n0   = blockIdx.x * 128;
  const int m0   = blockIdx.y * 128;
  const int wm   = (wave & 1) * 64;
  const int wn   = (wave >> 1) * 64;
  const int NKB  = K >> 5;               // k-32 blocks (24 or 96, even)
  const int MBmax = (M >> 5) - 1;

  const int8_t* apt[2]; const int8_t* bpt[2];
#pragma unroll
  for (int mi = 0; mi < 2; mi++){
    int rb = (m0 + wm + mi * 32) >> 5; if (rb > MBmax) rb = MBmax;  // clamp (dup frag, never stored)
    apt[mi] = Af + ((size_t)rb * NKB) * 1024 + lane * 16;
  }
#pragma unroll
  for (int nj = 0; nj < 2; nj++){
    int cb = (n0 + wn + nj * 32) >> 5;
    bpt[nj] = Bf + ((size_t)cb * NKB) * 1024 + lane * 16;
  }

  v16i acc[2][2] = {};
  v4i a0[2], b0[2], a1[2], b1[2];
#pragma unroll
  for (int mi = 0; mi < 2; mi++) a0[mi] = *(const v4i*)(apt[mi]);
#pragma unroll
  for (int nj = 0; nj < 2; nj++) b0[nj] = *(const v4i*)(bpt[nj]);

  for (int kb = 0; kb < NKB; kb += 2){
    const size_t o1 = (size_t)(kb + 1) << 10;
    const size_t o2 = (size_t)(kb + 2) << 10;
    // prefetch kb+1 (NKB even => always exists)
#pragma unroll
    for (int mi = 0; mi < 2; mi++) a1[mi] = *(const v4i*)(apt[mi] + o1);
#pragma unroll
    for (int nj = 0; nj < 2; nj++) b1[nj] = *(const v4i*)(bpt[nj] + o1);
#pragma unroll
    for (int mi = 0; mi < 2; mi++)
#pragma unroll
      for (int nj = 0; nj < 2; nj++)
        acc[mi][nj] = __builtin_amdgcn_mfma_i32_32x32x32_i8(a0[mi], b0[nj], acc[mi][nj], 0, 0, 0);
    if (kb + 2 < NKB){
#pragma unroll
      for (int mi = 0; mi < 2; mi++) a0[mi] = *(const v4i*)(apt[mi] + o2);
#pragma unroll
      for (int nj = 0; nj < 2; nj++) b0[nj] = *(const v4i*)(bpt[nj] + o2);
    }
#pragma unroll
    for (int mi = 0; mi < 2; mi++)
#pragma unroll
      for (int nj = 0; nj < 2; nj++)
        acc[mi][nj] = __builtin_amdgcn_mfma_i32_32x32x32_i8(a1[mi], b1[nj], acc[mi][nj], 0, 0, 0);
  }

  // epilogue scalars
  float s_h, off_h;
  if constexpr (MODE == 1){
    float gmin = dec_f(sc[1]), gmax = dec_f(sc[5]);
    float sg = fmaxf(gmax - gmin, 1e-8f) / 255.0f;
    float zp = rintf(-gmin / sg);
    float sw = fmaxf(__uint_as_float(sc[4]), 1e-8f) / 127.0f;
    s_h = sg * sw; off_h = 128.0f - zp;
  } else {
    float xmin = dec_f(sc[0]), xmax = dec_f(sc[2]);
    float sx = fmaxf(xmax - xmin, 1e-8f) / 255.0f;
    float zp = rintf(-xmin / sx);
    float sw = fmaxf(__uint_as_float(sc[3]), 1e-8f) / 127.0f;
    s_h = sx * sw; off_h = 128.0f - zp;
  }
  float qs = 1.0f, qzp = 0.0f;
  if constexpr (MODE == 2){
    float gmin = dec_f(sc[1]), gmax = dec_f(sc[5]);
    qs = fmaxf(gmax - gmin, 1e-8f) / 255.0f;
    qzp = rintf(-gmin / qs);
  }

  // C/D 32x32 layout: col = lane&31, row = (reg&3) + 8*(reg>>2) + 4*(lane>>5)
  float lmin = 3.4e38f, lmax = -3.4e38f;
#pragma unroll
  for (int nj = 0; nj < 2; nj++){
    const int n = n0 + wn + nj * 32 + l31;
    const float rsv = off_h * (float)rowsum[n];
    const float bv = bias[n];
#pragma unroll
    for (int mi = 0; mi < 2; mi++){
      const int mbase = m0 + wm + mi * 32 + 4 * kh;
#pragma unroll
      for (int r = 0; r < 16; r++){
        const int m = mbase + (r & 3) + 8 * (r >> 2);
        if (m < M){
          float h = s_h * ((float)acc[mi][nj][r] + rsv) + bv;
          if constexpr (MODE == 0){
            float gv = int_gelu_f(h);
            lmin = fminf(lmin, gv); lmax = fmaxf(lmax, gv);
          } else if constexpr (MODE == 3){
            float gv = int_gelu_f(h);
            lmin = fminf(lmin, gv); lmax = fmaxf(lmax, gv);
            size_t hidx = ((((size_t)(m >> 5)) * (N >> 5) + (n >> 5)) << 10)
                        + ((size_t)((n >> 4) & 1) << 9) + ((m & 31) << 4) + (n & 15);
            ((_Float16*)Cout)[hidx] = (_Float16)gv;
          } else if constexpr (MODE == 2){
            float gv = int_gelu_f(h);
            float qf = fminf(fmaxf(rintf(gv / qs) + qzp, 0.0f), 255.0f);
            size_t bidx = ((((size_t)(m >> 5)) * (N >> 5) + (n >> 5)) << 10)
                        + ((size_t)((n >> 4) & 1) << 9) + ((m & 31) << 4) + (n & 15);
            ((int8_t*)Cout)[bidx] = (int8_t)((int)qf - 128);
          } else {
            ((float*)Cout)[(size_t)m * N + n] = h;
          }
        }
      }
    }
  }

  if constexpr (MODE == 0 || MODE == 3){
    __shared__ float redA[256], redB[256];
    redA[tid] = lmin; redB[tid] = lmax;
    __syncthreads();
    for (int st = 128; st > 0; st >>= 1){
      if (tid < st){
        redA[tid] = fminf(redA[tid], redA[tid + st]);
        redB[tid] = fmaxf(redB[tid], redB[tid + st]);
      }
      __syncthreads();
    }
    if (tid == 0){
      atomicMin(&sc[1], enc_f(redA[0]));
      atomicMax(&sc[5], enc_f(redB[0]));
    }
  }
}

extern "C" void kernel_launch(void* const* d_in, const int* in_sizes, int n_in,
                              void* d_out, int out_size, void* d_ws, size_t ws_size,
                              hipStream_t stream)
{
  const float* x  = (const float*)d_in[0];
  const float* w1 = (const float*)d_in[1];
  const float* b1 = (const float*)d_in[2];
  const float* w2 = (const float*)d_in[3];
  const float* b2 = (const float*)d_in[4];
  float* out = (float*)d_out;

  const int H = in_sizes[2];            // 3072
  const int D = in_sizes[4];            // 768
  const int M = in_sizes[0] / D;        // 12608 (multiple of 32)

  char* ws = (char*)d_ws;
  unsigned* sc = (unsigned*)ws;
  size_t off = 256;
  int8_t* qx  = (int8_t*)(ws + off); off += (size_t)M * D;   // 9.68 MB  (fragmented)
  int8_t* qw1 = (int8_t*)(ws + off); off += (size_t)H * D;   // 2.36 MB  (fragmented)
  int8_t* qw2 = (int8_t*)(ws + off); off += (size_t)D * H;   // 2.36 MB  (fragmented)
  int* rs1 = (int*)(ws + off); off += (size_t)H * 4;
  int* rs2 = (int*)(ws + off); off += 4096;
  int8_t* qg  = (int8_t*)(ws + off); off += (size_t)M * H;   // 38.7 MB  (fragmented)
  _Float16* g16 = (_Float16*)(ws + off);                      // 77.5 MB  (fragmented fp16)
  const size_t need_big = off + (size_t)M * H * 2;
  (void)n_in; (void)out_size;

  // scalar init: slots 0,1 = 0xFFFFFFFF (encoded +inf for min); 2..5 = 0
  hipMemsetAsync(sc, 0xFF, 8, stream);
  hipMemsetAsync(sc + 2, 0x00, 16, stream);

  reduce_stats<<<dim3(1280), dim3(256), 0, stream>>>(
      (const float4*)x, M * D / 4,
      (const float4*)w1, H * D / 4,
      (const float4*)w2, D * H / 4, sc);

  quant_all<<<dim3(2048 + H + D), dim3(256), 0, stream>>>(
      x, qx, (long)M * D / 16,
      w1, w2, qw1, qw2, rs1, rs2, sc, H, D);

  const dim3 g1(H / 128, (M + 127) / 128), g2(D / 128, (M + 127) / 128), blk(256);

  if (ws_size >= need_big){
    // GEMM1 (single pass): g stats + store g fp16 (fragmented)
    gemm_i8f<3><<<g1, blk, 0, stream>>>(qx, qw1, rs1, b1, g16, M, H, D, sc);
    // recode g (frag fp16) -> qg (frag int8)
    quant_g<<<dim3(2048), dim3(256), 0, stream>>>(
        (const vh8*)g16, (uint4*)qg, (long)M * H / 16, sc);
  } else {
    // fallback: exact 2-pass GEMM1 (stats, then quantize)
    gemm_i8f<0><<<g1, blk, 0, stream>>>(qx, qw1, rs1, b1, nullptr, M, H, D, sc);
    gemm_i8f<2><<<g1, blk, 0, stream>>>(qx, qw1, rs1, b1, qg, M, H, D, sc);
  }

  // GEMM2: out = qg @ qw2^T + b2
  gemm_i8f<1><<<g2, blk, 0, stream>>>(qg, qw2, rs2, b2, out, M, D, H, sc);
}